// Round 9
// baseline (397.971 us; speedup 1.0000x reference)
//
#include <hip/hip_runtime.h>
#include <hip/hip_bf16.h>
#include <cstdint>

#define D_MODEL 1024
#define NHEADS 16
#define DHEAD 64
#define DMLP 4096
#define BATCH 2
#define SEQ 2048
#define ROWS (BATCH*SEQ)
#define LN_EPS 1e-5f

typedef __attribute__((ext_vector_type(8))) short short8;
typedef __attribute__((ext_vector_type(4))) float f32x4;

typedef const __attribute__((address_space(1))) uint32_t* gas_ptr;
typedef __attribute__((address_space(3))) uint32_t* las_ptr;

__device__ __forceinline__ short f2bf(float f) {
  union { float f; uint32_t u; } v; v.f = f;
  uint32_t r = v.u + 0x7FFFu + ((v.u >> 16) & 1u);
  return (short)(r >> 16);
}
__device__ __forceinline__ float bf2f(short s) {
  union { uint32_t u; float f; } v; v.u = ((uint32_t)(uint16_t)s) << 16;
  return v.f;
}

// ---------------- LayerNorm ----------------
__global__ void ln_kernel(const float* __restrict__ x, const float* __restrict__ w,
                          const float* __restrict__ b, short* __restrict__ out) {
  int row = blockIdx.x;
  int t = threadIdx.x;
  const float4 v = ((const float4*)(x + (size_t)row * D_MODEL))[t];
  float s = v.x + v.y + v.z + v.w;
  float s2 = v.x*v.x + v.y*v.y + v.z*v.z + v.w*v.w;
#pragma unroll
  for (int k = 1; k < 64; k <<= 1) { s += __shfl_xor(s, k); s2 += __shfl_xor(s2, k); }
  __shared__ float red[8];
  int wv = t >> 6;
  if ((t & 63) == 0) { red[wv] = s; red[wv + 4] = s2; }
  __syncthreads();
  s = red[0] + red[1] + red[2] + red[3];
  s2 = red[4] + red[5] + red[6] + red[7];
  float mu = s * (1.0f / D_MODEL);
  float var = s2 * (1.0f / D_MODEL) - mu * mu;
  float rstd = rsqrtf(var + LN_EPS);
  const float4 wv4 = ((const float4*)w)[t];
  const float4 bv4 = ((const float4*)b)[t];
  short4 o4;
  o4.x = f2bf((v.x - mu) * rstd * wv4.x + bv4.x);
  o4.y = f2bf((v.y - mu) * rstd * wv4.y + bv4.y);
  o4.z = f2bf((v.z - mu) * rstd * wv4.z + bv4.z);
  o4.w = f2bf((v.w - mu) * rstd * wv4.w + bv4.w);
  *(short4*)(out + (size_t)row * D_MODEL + t * 4) = o4;
}

// fused: out += part, then h2 = LN(out)  (replaces reduce1 + ln_kernel for WO)
__global__ void reduce_ln(float* __restrict__ out, const float* __restrict__ part,
                          const float* __restrict__ w, const float* __restrict__ b,
                          short* __restrict__ h2) {
  int row = blockIdx.x;
  int t = threadIdx.x;
  float4 v = ((float4*)(out + (size_t)row * D_MODEL))[t];
  const float4 q = ((const float4*)(part + (size_t)row * D_MODEL))[t];
  v.x += q.x; v.y += q.y; v.z += q.z; v.w += q.w;
  ((float4*)(out + (size_t)row * D_MODEL))[t] = v;
  float s = v.x + v.y + v.z + v.w;
  float s2 = v.x*v.x + v.y*v.y + v.z*v.z + v.w*v.w;
#pragma unroll
  for (int k = 1; k < 64; k <<= 1) { s += __shfl_xor(s, k); s2 += __shfl_xor(s2, k); }
  __shared__ float red[8];
  int wv = t >> 6;
  if ((t & 63) == 0) { red[wv] = s; red[wv + 4] = s2; }
  __syncthreads();
  s = red[0] + red[1] + red[2] + red[3];
  s2 = red[4] + red[5] + red[6] + red[7];
  float mu = s * (1.0f / D_MODEL);
  float var = s2 * (1.0f / D_MODEL) - mu * mu;
  float rstd = rsqrtf(var + LN_EPS);
  const float4 wv4 = ((const float4*)w)[t];
  const float4 bv4 = ((const float4*)b)[t];
  short4 o4;
  o4.x = f2bf((v.x - mu) * rstd * wv4.x + bv4.x);
  o4.y = f2bf((v.y - mu) * rstd * wv4.y + bv4.y);
  o4.z = f2bf((v.z - mu) * rstd * wv4.z + bv4.z);
  o4.w = f2bf((v.w - mu) * rstd * wv4.w + bv4.w);
  *(short4*)(h2 + (size_t)row * D_MODEL + t * 4) = o4;
}

// ---------------- Tiled transpose+convert ----------------
__global__ __launch_bounds__(256) void transpose_tile(const float* __restrict__ src, short* __restrict__ dst,
                                                      int R, int C, int srcMatStride) {
  __shared__ float tile[64][65];
  const int m = blockIdx.z;
  const int r0 = blockIdx.y * 64, c0 = blockIdx.x * 64;
  const int tx = threadIdx.x & 15, ty = threadIdx.x >> 4;
  const float* s = src + (size_t)m * srcMatStride + (size_t)r0 * C + c0;
#pragma unroll
  for (int i = 0; i < 4; i++) {
    float4 v = *(const float4*)(s + (size_t)(ty + i * 16) * C + tx * 4);
    tile[ty + i * 16][tx * 4 + 0] = v.x;
    tile[ty + i * 16][tx * 4 + 1] = v.y;
    tile[ty + i * 16][tx * 4 + 2] = v.z;
    tile[ty + i * 16][tx * 4 + 3] = v.w;
  }
  __syncthreads();
  short* d = dst + (size_t)m * C * R + (size_t)c0 * R + r0;
#pragma unroll
  for (int p = 0; p < 4; p++) {
    int c = ty + p * 16;
    int r4 = tx * 4;
    short4 o;
    o.x = f2bf(tile[r4 + 0][c]);
    o.y = f2bf(tile[r4 + 1][c]);
    o.z = f2bf(tile[r4 + 2][c]);
    o.w = f2bf(tile[r4 + 3][c]);
    *(short4*)(d + (size_t)c * R + r4) = o;
  }
}

// ---------------- bf16 MFMA GEMM, 128x128 tile, BK=32, B^T input ----------------
// A: LDS (2 buffers, 16 KB), conflict-free swizzled reads (verified 0-conflict).
// B: global -> REGISTER, per-wave software pipeline one K-step ahead (ping-pong
// bA[]/bB[], static indices). Removes B's LDS round-trip and half the
// barrier-gated staging. One vmcnt(0)+s_barrier per K-step.
// XCD N-stripe remap keeps each XCD's B-stripe L2-resident.
// EPI 0: bf16 store   EPI 2: bias+GELU->bf16
// EPI 5: split-K over blockIdx.z: z0 -> outf = v (+bias) + resid ; z1 -> part = v
template<int EPI>
__global__ __launch_bounds__(256) void gemm_bt(const short* __restrict__ A, const short* __restrict__ BT,
    const float* __restrict__ bias, const float* __restrict__ resid,
    float* __restrict__ outf, short* __restrict__ outb, float* __restrict__ part,
    int M, int N, int K, int LDA, int LDB) {
  __shared__ alignas(16) short As[2][4096];
  const int t = threadIdx.x;
  const int l = t & 63, w = t >> 6;
  const int l15 = l & 15, l4 = l >> 4;

  // XCD N-stripe remap (bijective; gridDim.x % 8 == 0 for all launches)
  const int nx = gridDim.x;
  const int sw = nx >> 3;
  int dd = blockIdx.y * nx + blockIdx.x;
  const int xcd = dd & 7, li = dd >> 3;
  const int bx = xcd * sw + (li % sw);
  const int by = li / sw;
  const int row0 = by * 128, col0 = bx * 128;

  if (EPI == 5) {
    A  += (size_t)blockIdx.z * K;
    BT += (size_t)blockIdx.z * K;
  }
  f32x4 acc[4][4] = {};

  const int gr = w * 16 + (l >> 2);
  const int c8 = ((l & 3) ^ ((l >> 3) & 3)) * 8;
  const short* Ab0 = A + (size_t)(row0 + gr) * LDA + c8;
  const short* Ab1 = A + (size_t)(row0 + 64 + gr) * LDA + c8;
  char* AsB = (char*)As;
  const int soff = w * 1024 + l * 16;

  const int wr = (w >> 1) * 64, wc = (w & 1) * 64;
  const short* Bp = BT + (size_t)(col0 + wc + l15) * LDB + l4 * 8;
  const size_t bstep = (size_t)16 * LDB;

  const int rch = (l4 ^ ((l15 >> 1) & 3)) * 16;
  const char* Arow = AsB + (wr >> 6) * 4096 + l15 * 64 + rch;

  short8 bA[4], bB[4];
  const int nk = K >> 5;

  // prologue: B(0) -> bA; stage A(0) -> buf0
#pragma unroll
  for (int n = 0; n < 4; n++) bA[n] = *(const short8*)(Bp + n * bstep);
  __builtin_amdgcn_global_load_lds((gas_ptr)(Ab0), (las_ptr)(AsB + soff),        16, 0, 0);
  __builtin_amdgcn_global_load_lds((gas_ptr)(Ab1), (las_ptr)(AsB + 4096 + soff), 16, 0, 0);
  asm volatile("s_waitcnt vmcnt(0)" ::: "memory");
  __builtin_amdgcn_s_barrier();

  int ti = 0;
  while (true) {
    { // even step: compute buf0 with bA; prefetch ti+1 -> buf1, bB
      if (ti + 1 < nk) {
        const short* Bn = Bp + (ti + 1) * 32;
#pragma unroll
        for (int n = 0; n < 4; n++) bB[n] = *(const short8*)(Bn + n * bstep);
        const int k0 = (ti + 1) << 5;
        __builtin_amdgcn_global_load_lds((gas_ptr)(Ab0 + k0), (las_ptr)(AsB + 8192 + soff),        16, 0, 0);
        __builtin_amdgcn_global_load_lds((gas_ptr)(Ab1 + k0), (las_ptr)(AsB + 8192 + 4096 + soff), 16, 0, 0);
      }
      short8 a[4];
#pragma unroll
      for (int m = 0; m < 4; m++) a[m] = *(const short8*)(Arow + m * 1024);
      __builtin_amdgcn_s_setprio(1);
#pragma unroll
      for (int m = 0; m < 4; m++)
#pragma unroll
        for (int n = 0; n < 4; n++)
          acc[m][n] = __builtin_amdgcn_mfma_f32_16x16x32_bf16(a[m], bA[n], acc[m][n], 0, 0, 0);
      __builtin_amdgcn_s_setprio(0);
      if (ti + 1 < nk) {
        asm volatile("s_waitcnt vmcnt(0)" ::: "memory");
        __builtin_amdgcn_s_barrier();
      }
    }
    if (++ti >= nk) break;
    { // odd step: compute buf1 with bB; prefetch ti+1 -> buf0, bA
      if (ti + 1 < nk) {
        const short* Bn = Bp + (ti + 1) * 32;
#pragma unroll
        for (int n = 0; n < 4; n++) bA[n] = *(const short8*)(Bn + n * bstep);
        const int k0 = (ti + 1) << 5;
        __builtin_amdgcn_global_load_lds((gas_ptr)(Ab0 + k0), (las_ptr)(AsB + soff),        16, 0, 0);
        __builtin_amdgcn_global_load_lds((gas_ptr)(Ab1 + k0), (las_ptr)(AsB + 4096 + soff), 16, 0, 0);
      }
      short8 a[4];
#pragma unroll
      for (int m = 0; m < 4; m++) a[m] = *(const short8*)(Arow + 8192 + m * 1024);
      __builtin_amdgcn_s_setprio(1);
#pragma unroll
      for (int m = 0; m < 4; m++)
#pragma unroll
        for (int n = 0; n < 4; n++)
          acc[m][n] = __builtin_amdgcn_mfma_f32_16x16x32_bf16(a[m], bB[n], acc[m][n], 0, 0, 0);
      __builtin_amdgcn_s_setprio(0);
      if (ti + 1 < nk) {
        asm volatile("s_waitcnt vmcnt(0)" ::: "memory");
        __builtin_amdgcn_s_barrier();
      }
    }
    if (++ti >= nk) break;
  }

  // epilogue: D[row][col], row=l4*4+j, col=l15 per 16x16 fragment
#pragma unroll
  for (int m = 0; m < 4; m++) {
#pragma unroll
    for (int n = 0; n < 4; n++) {
#pragma unroll
      for (int j = 0; j < 4; j++) {
        int R_ = row0 + wr + m * 16 + l4 * 4 + j;
        int C_ = col0 + wc + n * 16 + l15;
        float v = acc[m][n][j];
        size_t o = (size_t)R_ * N + C_;
        if (EPI == 0) {
          outb[o] = f2bf(v);
        } else if (EPI == 2) {
          float xx = v + bias[C_];
          outb[o] = f2bf(0.5f * xx * (1.0f + erff(xx * 0.70710678118f)));
        } else if (EPI == 5) {
          if (blockIdx.z == 0) outf[o] = v + (bias ? bias[C_] : 0.0f) + resid[o];
          else part[o] = v;
        }
      }
    }
  }
}

// split-K reduce: out += part
__global__ void reduce1(float* __restrict__ out, const float* __restrict__ p, int n4) {
  for (int i = blockIdx.x * 256 + threadIdx.x; i < n4; i += gridDim.x * 256) {
    float4 o = ((float4*)out)[i];
    float4 q = ((const float4*)p)[i];
    o.x += q.x; o.y += q.y; o.z += q.z; o.w += q.w;
    ((float4*)out)[i] = o;
  }
}

// ---------------- MFMA flash attention, 2-phase pipelined ----------------
__device__ __forceinline__ void attn_step(
    int kt_, int qt, int bufP,
    const short* __restrict__ base, const short* __restrict__ vbase,
    short8& vWA, short8& vWB,
    short8& vLA, short8& vLB,
    const short8 qf[2],
    char* KsB, char* VtB, char* PlB,
    f32x4 acc[4], float mrun[4], float lrun[4],
    int w, int l, int q0, int vr, int vd0)
{
  const int l15 = l & 15, l4 = l >> 4;
  const int bufQ = bufP ^ 1;
  if (kt_ < qt) {
#pragma unroll
    for (int i = 0; i < 8; i++) {
      int d = vd0 + i;
      int cs = (vr >> 2) ^ ((d >> 3) & 7);
      uint32_t val = (uint32_t)(uint16_t)vWA[i] | ((uint32_t)(uint16_t)vWB[i] << 16);
      *(uint32_t*)(VtB + bufQ * 9216 + d * 144 + cs * 16 + (vr & 3) * 4) = val;
    }
#pragma unroll
    for (int i = 0; i < 2; i++) {
      int g = (w * 2 + i) * 64 + l;
      int key = g >> 3, ck = g & 7;
      const short* src = base + (size_t)((kt_ + 1) * 64 + key) * 3072 + 1024 + ((ck ^ (key & 7)) * 8);
      __builtin_amdgcn_global_load_lds((gas_ptr)src, (las_ptr)(KsB + bufQ * 8192 + g * 16), 16, 0, 0);
    }
  }
  if (kt_ + 2 <= qt) {
    vLA = *(const short8*)(vbase + (size_t)((kt_ + 2) * 64 + 2 * vr) * 3072);
    vLB = *(const short8*)(vbase + (size_t)((kt_ + 2) * 64 + 2 * vr + 1) * 3072);
  }

  f32x4 sc[4];
#pragma unroll
  for (int cb = 0; cb < 4; cb++) {
    f32x4 s = {};
    int key = cb * 16 + l15;
#pragma unroll
    for (int c = 0; c < 2; c++) {
      int ck = (c * 4 + l4) ^ (key & 7);
      short8 kf = *(const short8*)(KsB + bufP * 8192 + key * 128 + ck * 16);
      s = __builtin_amdgcn_mfma_f32_16x16x32_bf16(qf[c], kf, s, 0, 0, 0);
    }
    sc[cb] = s;
  }

  const bool lastt = (kt_ == qt);
  float alpha[4];
#pragma unroll
  for (int jj = 0; jj < 4; jj++) {
    int qg = q0 + l4 * 4 + jj;
    float s0 = sc[0][jj] * 0.125f;
    float s1 = sc[1][jj] * 0.125f;
    float s2 = sc[2][jj] * 0.125f;
    float s3 = sc[3][jj] * 0.125f;
    if (lastt) {
      int kg = kt_ * 64 + l15;
      if (kg      > qg) s0 = -1e30f;
      if (kg + 16 > qg) s1 = -1e30f;
      if (kg + 32 > qg) s2 = -1e30f;
      if (kg + 48 > qg) s3 = -1e30f;
    }
    float rm = fmaxf(fmaxf(s0, s1), fmaxf(s2, s3));
    rm = fmaxf(rm, __shfl_xor(rm, 1));
    rm = fmaxf(rm, __shfl_xor(rm, 2));
    rm = fmaxf(rm, __shfl_xor(rm, 4));
    rm = fmaxf(rm, __shfl_xor(rm, 8));
    float nm = fmaxf(mrun[jj], rm);
    float al = __expf(mrun[jj] - nm);
    mrun[jj] = nm;
    float p0 = __expf(s0 - nm), p1 = __expf(s1 - nm);
    float p2 = __expf(s2 - nm), p3 = __expf(s3 - nm);
    float ps = p0 + p1 + p2 + p3;
    ps += __shfl_xor(ps, 1);
    ps += __shfl_xor(ps, 2);
    ps += __shfl_xor(ps, 4);
    ps += __shfl_xor(ps, 8);
    lrun[jj] = lrun[jj] * al + ps;
    alpha[jj] = al;
    short* pr = (short*)(PlB + (l4 * 4 + jj) * 144);
    pr[l15]      = f2bf(p0);
    pr[16 + l15] = f2bf(p1);
    pr[32 + l15] = f2bf(p2);
    pr[48 + l15] = f2bf(p3);
  }
#pragma unroll
  for (int db = 0; db < 4; db++) {
    f32x4 a = acc[db];
    a[0] *= alpha[0]; a[1] *= alpha[1]; a[2] *= alpha[2]; a[3] *= alpha[3];
    acc[db] = a;
  }
#pragma unroll
  for (int kc = 0; kc < 2; kc++) {
    short8 pf = *(const short8*)(PlB + l15 * 144 + kc * 64 + l4 * 16);
#pragma unroll
    for (int db = 0; db < 4; db++) {
      int d = db * 16 + l15;
      int cs = (kc * 4 + l4) ^ ((d >> 3) & 7);
      short8 vf = *(const short8*)(VtB + bufP * 9216 + d * 144 + cs * 16);
      acc[db] = __builtin_amdgcn_mfma_f32_16x16x32_bf16(pf, vf, acc[db], 0, 0, 0);
    }
  }
}

__global__ __launch_bounds__(256) void attn_mfma(const short* __restrict__ qkv, short* __restrict__ ctx) {
  __shared__ alignas(16) short Ks[2 * 64 * 64];
  __shared__ alignas(16) short Vt[2 * 64 * 72];
  __shared__ alignas(16) short Pl[4][16 * 72];
  const int t = threadIdx.x;
  const int l = t & 63;
  const int w = t >> 6;
  const int l15 = l & 15, l4 = l >> 4;
  const int bh = blockIdx.x;
  const int b = bh >> 4, h = bh & 15;
  const int qt = (gridDim.y - 1) - blockIdx.y;
  const int q0 = qt * 64 + w * 16;

  const short* base = qkv + (size_t)b * SEQ * 3072 + h * 64;

  short8 qf[2];
#pragma unroll
  for (int c = 0; c < 2; c++)
    qf[c] = *(const short8*)(base + (size_t)(q0 + l15) * 3072 + c * 32 + l4 * 8);

  const int vr = t >> 3;
  const int vd0 = (t & 7) * 8;
  const short* vbase = base + 2048 + vd0;

  char* KsB = (char*)Ks;
  char* VtB = (char*)Vt;
  char* PlB = (char*)&Pl[w][0];

  short8 va0, vb0, va1, vb1;
  va0 = *(const short8*)(vbase + (size_t)(2 * vr) * 3072);
  vb0 = *(const short8*)(vbase + (size_t)(2 * vr + 1) * 3072);
  if (qt >= 1) {
    va1 = *(const short8*)(vbase + (size_t)(64 + 2 * vr) * 3072);
    vb1 = *(const short8*)(vbase + (size_t)(64 + 2 * vr + 1) * 3072);
  }
#pragma unroll
  for (int i = 0; i < 8; i++) {
    int d = vd0 + i;
    int cs = (vr >> 2) ^ ((d >> 3) & 7);
    uint32_t val = (uint32_t)(uint16_t)va0[i] | ((uint32_t)(uint16_t)vb0[i] << 16);
    *(uint32_t*)(VtB + d * 144 + cs * 16 + (vr & 3) * 4) = val;
  }
#pragma unroll
  for (int i = 0; i < 2; i++) {
    int g = (w * 2 + i) * 64 + l;
    int key = g >> 3, ck = g & 7;
    const short* src = base + (size_t)key * 3072 + 1024 + ((ck ^ (key & 7)) * 8);
    __builtin_amdgcn_global_load_lds((gas_ptr)src, (las_ptr)(KsB + g * 16), 16, 0, 0);
  }
  __syncthreads();

  f32x4 acc[4] = {};
  float mrun[4] = {-1e30f, -1e30f, -1e30f, -1e30f};
  float lrun[4] = {0.f, 0.f, 0.f, 0.f};

  int kt = 0;
  while (true) {
    attn_step(kt, qt, 0, base, vbase, va1, vb1, va0, vb0, qf,
              KsB, VtB, PlB, acc, mrun, lrun, w, l, q0, vr, vd0);
    __syncthreads();
    if (++kt > qt) break;
    attn_step(kt, qt, 1, base, vbase, va0, vb0, va1, vb1, qf,
              KsB, VtB, PlB, acc, mrun, lrun, w, l, q0, vr, vd0);
    __syncthreads();
    if (++kt > qt) break;
  }

  float inv[4];
#pragma unroll
  for (int jj = 0; jj < 4; jj++) inv[jj] = 1.0f / lrun[jj];
  short* obase = ctx + (size_t)(b * SEQ + q0) * D_MODEL + h * 64;
#pragma unroll
  for (int db = 0; db < 4; db++)
#pragma unroll
    for (int jj = 0; jj < 4; jj++)
      obase[(size_t)(l4 * 4 + jj) * D_MODEL + db * 16 + l15] = f2bf(acc[db][jj] * inv[jj]);
}

extern "C" void kernel_launch(void* const* d_in, const int* in_sizes, int n_in,
                              void* d_out, int out_size, void* d_ws, size_t ws_size,
                              hipStream_t stream) {
  (void)in_sizes; (void)n_in; (void)out_size; (void)ws_size;
  const float* x    = (const float*)d_in[0];
  const float* WQ   = (const float*)d_in[1];
  const float* WK   = (const float*)d_in[2];
  const float* WV   = (const float*)d_in[3];
  const float* WO   = (const float*)d_in[4];
  const float* W1   = (const float*)d_in[5];
  const float* b1   = (const float*)d_in[6];
  const float* W2   = (const float*)d_in[7];
  const float* b2   = (const float*)d_in[8];
  const float* ln1w = (const float*)d_in[9];
  const float* ln1b = (const float*)d_in[10];
  const float* ln2w = (const float*)d_in[11];
  const float* ln2b = (const float*)d_in[12];
  float* out = (float*)d_out;

  char* p = (char*)d_ws;
  short* h1    = (short*)p; p += (size_t)ROWS * D_MODEL * 2;        // 8 MB
  short* ctx   = (short*)p; p += (size_t)ROWS * D_MODEL * 2;        // 8 MB
  short* h2    = (short*)p; p += (size_t)ROWS * D_MODEL * 2;        // 8 MB
  short* m1    = (short*)p; p += (size_t)ROWS * DMLP * 2;           // 32 MB
  short* wqkvT = (short*)p; p += (size_t)3 * D_MODEL * D_MODEL * 2; // 6 MB
  short* woT   = (short*)p; p += (size_t)D_MODEL * D_MODEL * 2;     // 2 MB
  short* w1T   = (short*)p; p += (size_t)D_MODEL * DMLP * 2;        // 8 MB
  short* w2T   = (short*)p; p += (size_t)D_MODEL * DMLP * 2;        // 8 MB
  short* qkv   = (short*)p; p += (size_t)ROWS * 3 * D_MODEL * 2;    // 24 MB

  // split-K partial (16 MB f32) in qkv region (dead after attention)
  float* fp1 = (float*)qkv;

  // weight repacks (bf16, B^T layout)
  transpose_tile<<<dim3(1, 16, 16), 256, 0, stream>>>(WQ, wqkvT,                   1024, 64, D_MODEL * DHEAD);
  transpose_tile<<<dim3(1, 16, 16), 256, 0, stream>>>(WK, wqkvT + 1024 * 1024,     1024, 64, D_MODEL * DHEAD);
  transpose_tile<<<dim3(1, 16, 16), 256, 0, stream>>>(WV, wqkvT + 2 * 1024 * 1024, 1024, 64, D_MODEL * DHEAD);
  transpose_tile<<<dim3(16, 16, 1), 256, 0, stream>>>(WO, woT, 1024, 1024, 0);
  transpose_tile<<<dim3(64, 16, 1), 256, 0, stream>>>(W1, w1T, 1024, 4096, 0);
  transpose_tile<<<dim3(16, 64, 1), 256, 0, stream>>>(W2, w2T, 4096, 1024, 0);

  // LN1
  ln_kernel<<<ROWS, 256, 0, stream>>>(x, ln1w, ln1b, h1);
  // QKV projection -> bf16 qkv  (nx=24)
  gemm_bt<0><<<dim3(3 * D_MODEL / 128, ROWS / 128), 256, 0, stream>>>(
      h1, wqkvT, nullptr, nullptr, nullptr, qkv, nullptr,
      ROWS, 3 * D_MODEL, D_MODEL, D_MODEL, D_MODEL);
  // attention
  attn_mfma<<<dim3(BATCH * NHEADS, SEQ / 64), 256, 0, stream>>>(qkv, ctx);
  // output projection, split-K z=2: z0 -> out = v + x ; z1 -> fp1  (nx=8)
  gemm_bt<5><<<dim3(D_MODEL / 128, ROWS / 128, 2), 256, 0, stream>>>(
      ctx, woT, nullptr, x, out, nullptr, fp1,
      ROWS, D_MODEL, D_MODEL / 2, D_MODEL, D_MODEL);
  // fused: out += fp1 ; h2 = LN2(out)
  reduce_ln<<<ROWS, 256, 0, stream>>>(out, fp1, ln2w, ln2b, h2);
  // MLP fc1 + GELU -> bf16 m1  (nx=32)
  gemm_bt<2><<<dim3(DMLP / 128, ROWS / 128), 256, 0, stream>>>(
      h2, w1T, b1, nullptr, nullptr, m1, nullptr,
      ROWS, DMLP, D_MODEL, D_MODEL, D_MODEL);
  // MLP fc2, split-K z=2: z0 -> out = v + b2 + resid(out) ; z1 -> fp1  (nx=8)
  gemm_bt<5><<<dim3(D_MODEL / 128, ROWS / 128, 2), 256, 0, stream>>>(
      m1, w2T, b2, out, out, nullptr, fp1,
      ROWS, D_MODEL, DMLP / 2, DMLP, DMLP);
  reduce1<<<2048, 256, 0, stream>>>(out, fp1, ROWS * D_MODEL / 4);
}

// Round 10
// 297.500 us; speedup vs baseline: 1.3377x; 1.3377x over previous
//
#include <hip/hip_runtime.h>
#include <hip/hip_bf16.h>
#include <cstdint>

#define D_MODEL 1024
#define NHEADS 16
#define DHEAD 64
#define DMLP 4096
#define BATCH 2
#define SEQ 2048
#define ROWS (BATCH*SEQ)
#define LN_EPS 1e-5f

typedef __attribute__((ext_vector_type(8))) short short8;
typedef __attribute__((ext_vector_type(4))) float f32x4;

typedef const __attribute__((address_space(1))) uint32_t* gas_ptr;
typedef __attribute__((address_space(3))) uint32_t* las_ptr;

__device__ __forceinline__ short f2bf(float f) {
  union { float f; uint32_t u; } v; v.f = f;
  uint32_t r = v.u + 0x7FFFu + ((v.u >> 16) & 1u);
  return (short)(r >> 16);
}
__device__ __forceinline__ float bf2f(short s) {
  union { uint32_t u; float f; } v; v.u = ((uint32_t)(uint16_t)s) << 16;
  return v.f;
}

// ---------------- LayerNorm ----------------
__global__ void ln_kernel(const float* __restrict__ x, const float* __restrict__ w,
                          const float* __restrict__ b, short* __restrict__ out) {
  int row = blockIdx.x;
  int t = threadIdx.x;
  const float4 v = ((const float4*)(x + (size_t)row * D_MODEL))[t];
  float s = v.x + v.y + v.z + v.w;
  float s2 = v.x*v.x + v.y*v.y + v.z*v.z + v.w*v.w;
#pragma unroll
  for (int k = 1; k < 64; k <<= 1) { s += __shfl_xor(s, k); s2 += __shfl_xor(s2, k); }
  __shared__ float red[8];
  int wv = t >> 6;
  if ((t & 63) == 0) { red[wv] = s; red[wv + 4] = s2; }
  __syncthreads();
  s = red[0] + red[1] + red[2] + red[3];
  s2 = red[4] + red[5] + red[6] + red[7];
  float mu = s * (1.0f / D_MODEL);
  float var = s2 * (1.0f / D_MODEL) - mu * mu;
  float rstd = rsqrtf(var + LN_EPS);
  const float4 wv4 = ((const float4*)w)[t];
  const float4 bv4 = ((const float4*)b)[t];
  short4 o4;
  o4.x = f2bf((v.x - mu) * rstd * wv4.x + bv4.x);
  o4.y = f2bf((v.y - mu) * rstd * wv4.y + bv4.y);
  o4.z = f2bf((v.z - mu) * rstd * wv4.z + bv4.z);
  o4.w = f2bf((v.w - mu) * rstd * wv4.w + bv4.w);
  *(short4*)(out + (size_t)row * D_MODEL + t * 4) = o4;
}

// fused: out += part, then h2 = LN(out)
__global__ void reduce_ln(float* __restrict__ out, const float* __restrict__ part,
                          const float* __restrict__ w, const float* __restrict__ b,
                          short* __restrict__ h2) {
  int row = blockIdx.x;
  int t = threadIdx.x;
  float4 v = ((float4*)(out + (size_t)row * D_MODEL))[t];
  const float4 q = ((const float4*)(part + (size_t)row * D_MODEL))[t];
  v.x += q.x; v.y += q.y; v.z += q.z; v.w += q.w;
  ((float4*)(out + (size_t)row * D_MODEL))[t] = v;
  float s = v.x + v.y + v.z + v.w;
  float s2 = v.x*v.x + v.y*v.y + v.z*v.z + v.w*v.w;
#pragma unroll
  for (int k = 1; k < 64; k <<= 1) { s += __shfl_xor(s, k); s2 += __shfl_xor(s2, k); }
  __shared__ float red[8];
  int wv = t >> 6;
  if ((t & 63) == 0) { red[wv] = s; red[wv + 4] = s2; }
  __syncthreads();
  s = red[0] + red[1] + red[2] + red[3];
  s2 = red[4] + red[5] + red[6] + red[7];
  float mu = s * (1.0f / D_MODEL);
  float var = s2 * (1.0f / D_MODEL) - mu * mu;
  float rstd = rsqrtf(var + LN_EPS);
  const float4 wv4 = ((const float4*)w)[t];
  const float4 bv4 = ((const float4*)b)[t];
  short4 o4;
  o4.x = f2bf((v.x - mu) * rstd * wv4.x + bv4.x);
  o4.y = f2bf((v.y - mu) * rstd * wv4.y + bv4.y);
  o4.z = f2bf((v.z - mu) * rstd * wv4.z + bv4.z);
  o4.w = f2bf((v.w - mu) * rstd * wv4.w + bv4.w);
  *(short4*)(h2 + (size_t)row * D_MODEL + t * 4) = o4;
}

// ---------------- Tiled transpose+convert ----------------
__global__ __launch_bounds__(256) void transpose_tile(const float* __restrict__ src, short* __restrict__ dst,
                                                      int R, int C, int srcMatStride) {
  __shared__ float tile[64][65];
  const int m = blockIdx.z;
  const int r0 = blockIdx.y * 64, c0 = blockIdx.x * 64;
  const int tx = threadIdx.x & 15, ty = threadIdx.x >> 4;
  const float* s = src + (size_t)m * srcMatStride + (size_t)r0 * C + c0;
#pragma unroll
  for (int i = 0; i < 4; i++) {
    float4 v = *(const float4*)(s + (size_t)(ty + i * 16) * C + tx * 4);
    tile[ty + i * 16][tx * 4 + 0] = v.x;
    tile[ty + i * 16][tx * 4 + 1] = v.y;
    tile[ty + i * 16][tx * 4 + 2] = v.z;
    tile[ty + i * 16][tx * 4 + 3] = v.w;
  }
  __syncthreads();
  short* d = dst + (size_t)m * C * R + (size_t)c0 * R + r0;
#pragma unroll
  for (int p = 0; p < 4; p++) {
    int c = ty + p * 16;
    int r4 = tx * 4;
    short4 o;
    o.x = f2bf(tile[r4 + 0][c]);
    o.y = f2bf(tile[r4 + 1][c]);
    o.z = f2bf(tile[r4 + 2][c]);
    o.w = f2bf(tile[r4 + 3][c]);
    *(short4*)(d + (size_t)c * R + r4) = o;
  }
}

// ---------------- bf16 MFMA GEMM, 128x128 tile, BK=64, B^T input ----------------
// 2 LDS buffers (A+B, 32KB each buf pair), ONE vmcnt(0)+s_barrier per 64-K tile
// (half the barrier convoys of BK=32). Per buffer: [128 rows][8 slots x 16B];
// slot sp of row gr holds source k-chunk sp^(gr&7) (pre-swizzled global src,
// linear gload_lds dest); read slot (kg*4+l4)^(l15&7) — measured 0-conflict.
// EPI 0: bf16 store   EPI 2: bias+GELU->bf16
// EPI 5: split-K over blockIdx.z: z0 -> outf = v (+bias) + resid ; z1 -> part = v
template<int EPI>
__global__ __launch_bounds__(256) void gemm_bt(const short* __restrict__ A, const short* __restrict__ BT,
    const float* __restrict__ bias, const float* __restrict__ resid,
    float* __restrict__ outf, short* __restrict__ outb, float* __restrict__ part,
    int M, int N, int K, int LDA, int LDB) {
  __shared__ alignas(16) short As[2][8192];
  __shared__ alignas(16) short Bs[2][8192];
  const int t = threadIdx.x;
  const int l = t & 63, w = t >> 6;
  const int l15 = l & 15, l4 = l >> 4;

  // XCD N-stripe remap (bijective; gridDim.x % 8 == 0 for all launches)
  const int nx = gridDim.x;
  const int sw = nx >> 3;
  int dd = blockIdx.y * nx + blockIdx.x;
  const int xcd = dd & 7, li = dd >> 3;
  const int bx = xcd * sw + (li % sw);
  const int by = li / sw;
  const int row0 = by * 128, col0 = bx * 128;

  if (EPI == 5) {
    A  += (size_t)blockIdx.z * K;
    BT += (size_t)blockIdx.z * K;
  }
  f32x4 acc[4][4] = {};

  char* AsB = (char*)As;
  char* BsB = (char*)Bs;

  // staging: granule g=(i*4+w)*64+l (i=0..3): row gr=g>>3, slot sp=g&7,
  // source chunk (sp^(gr&7))*8 elems; dest lane-linear at g*16.
  auto stg = [&](int ti) {
    const int bo = (ti & 1) * 16384;
    const int k0 = ti << 6;
#pragma unroll
    for (int i = 0; i < 4; i++) {
      const int g = (i * 4 + w) * 64 + l;
      const int gr = g >> 3, sp = g & 7;
      const int co = k0 + ((sp ^ (gr & 7)) << 3);
      __builtin_amdgcn_global_load_lds((gas_ptr)(A  + (size_t)(row0 + gr) * LDA + co),
                                       (las_ptr)(AsB + bo + g * 16), 16, 0, 0);
      __builtin_amdgcn_global_load_lds((gas_ptr)(BT + (size_t)(col0 + gr) * LDB + co),
                                       (las_ptr)(BsB + bo + g * 16), 16, 0, 0);
    }
  };

  const int nk = K >> 6;
  stg(0);
  asm volatile("s_waitcnt vmcnt(0)" ::: "memory");
  __builtin_amdgcn_s_barrier();

  const int wr = (w >> 1) * 64, wc = (w & 1) * 64;

  for (int ti = 0; ti < nk; ti++) {
    const int bo = (ti & 1) * 16384;
    if (ti + 1 < nk) stg(ti + 1);
#pragma unroll
    for (int kg = 0; kg < 2; kg++) {
      const int sl = ((kg * 4 + l4) ^ (l15 & 7)) * 16;
      short8 a[4], bfr[4];
#pragma unroll
      for (int m = 0; m < 4; m++) a[m]   = *(const short8*)(AsB + bo + (wr + m * 16 + l15) * 128 + sl);
#pragma unroll
      for (int n = 0; n < 4; n++) bfr[n] = *(const short8*)(BsB + bo + (wc + n * 16 + l15) * 128 + sl);
#pragma unroll
      for (int m = 0; m < 4; m++)
#pragma unroll
        for (int n = 0; n < 4; n++)
          acc[m][n] = __builtin_amdgcn_mfma_f32_16x16x32_bf16(a[m], bfr[n], acc[m][n], 0, 0, 0);
    }
    if (ti + 1 < nk) { asm volatile("s_waitcnt vmcnt(0)" ::: "memory"); }
    __builtin_amdgcn_s_barrier();
  }

  // epilogue: D[row][col], row=l4*4+j, col=l15 per 16x16 fragment
#pragma unroll
  for (int m = 0; m < 4; m++) {
#pragma unroll
    for (int n = 0; n < 4; n++) {
#pragma unroll
      for (int j = 0; j < 4; j++) {
        int R_ = row0 + wr + m * 16 + l4 * 4 + j;
        int C_ = col0 + wc + n * 16 + l15;
        float v = acc[m][n][j];
        size_t o = (size_t)R_ * N + C_;
        if (EPI == 0) {
          outb[o] = f2bf(v);
        } else if (EPI == 2) {
          float xx = v + bias[C_];
          outb[o] = f2bf(0.5f * xx * (1.0f + erff(xx * 0.70710678118f)));
        } else if (EPI == 5) {
          if (blockIdx.z == 0) outf[o] = v + (bias ? bias[C_] : 0.0f) + resid[o];
          else part[o] = v;
        }
      }
    }
  }
}

// split-K reduce: out += part
__global__ void reduce1(float* __restrict__ out, const float* __restrict__ p, int n4) {
  for (int i = blockIdx.x * 256 + threadIdx.x; i < n4; i += gridDim.x * 256) {
    float4 o = ((float4*)out)[i];
    float4 q = ((const float4*)p)[i];
    o.x += q.x; o.y += q.y; o.z += q.z; o.w += q.w;
    ((float4*)out)[i] = o;
  }
}

// ---------------- MFMA flash attention, 2-phase pipelined ----------------
__device__ __forceinline__ void attn_step(
    int kt_, int qt, int bufP,
    const short* __restrict__ base, const short* __restrict__ vbase,
    short8& vWA, short8& vWB,
    short8& vLA, short8& vLB,
    const short8 qf[2],
    char* KsB, char* VtB, char* PlB,
    f32x4 acc[4], float mrun[4], float lrun[4],
    int w, int l, int q0, int vr, int vd0)
{
  const int l15 = l & 15, l4 = l >> 4;
  const int bufQ = bufP ^ 1;
  if (kt_ < qt) {
#pragma unroll
    for (int i = 0; i < 8; i++) {
      int d = vd0 + i;
      int cs = (vr >> 2) ^ ((d >> 3) & 7);
      uint32_t val = (uint32_t)(uint16_t)vWA[i] | ((uint32_t)(uint16_t)vWB[i] << 16);
      *(uint32_t*)(VtB + bufQ * 9216 + d * 144 + cs * 16 + (vr & 3) * 4) = val;
    }
#pragma unroll
    for (int i = 0; i < 2; i++) {
      int g = (w * 2 + i) * 64 + l;
      int key = g >> 3, ck = g & 7;
      const short* src = base + (size_t)((kt_ + 1) * 64 + key) * 3072 + 1024 + ((ck ^ (key & 7)) * 8);
      __builtin_amdgcn_global_load_lds((gas_ptr)src, (las_ptr)(KsB + bufQ * 8192 + g * 16), 16, 0, 0);
    }
  }
  if (kt_ + 2 <= qt) {
    vLA = *(const short8*)(vbase + (size_t)((kt_ + 2) * 64 + 2 * vr) * 3072);
    vLB = *(const short8*)(vbase + (size_t)((kt_ + 2) * 64 + 2 * vr + 1) * 3072);
  }

  f32x4 sc[4];
#pragma unroll
  for (int cb = 0; cb < 4; cb++) {
    f32x4 s = {};
    int key = cb * 16 + l15;
#pragma unroll
    for (int c = 0; c < 2; c++) {
      int ck = (c * 4 + l4) ^ (key & 7);
      short8 kf = *(const short8*)(KsB + bufP * 8192 + key * 128 + ck * 16);
      s = __builtin_amdgcn_mfma_f32_16x16x32_bf16(qf[c], kf, s, 0, 0, 0);
    }
    sc[cb] = s;
  }

  const bool lastt = (kt_ == qt);
  float alpha[4];
#pragma unroll
  for (int jj = 0; jj < 4; jj++) {
    int qg = q0 + l4 * 4 + jj;
    float s0 = sc[0][jj] * 0.125f;
    float s1 = sc[1][jj] * 0.125f;
    float s2 = sc[2][jj] * 0.125f;
    float s3 = sc[3][jj] * 0.125f;
    if (lastt) {
      int kg = kt_ * 64 + l15;
      if (kg      > qg) s0 = -1e30f;
      if (kg + 16 > qg) s1 = -1e30f;
      if (kg + 32 > qg) s2 = -1e30f;
      if (kg + 48 > qg) s3 = -1e30f;
    }
    float rm = fmaxf(fmaxf(s0, s1), fmaxf(s2, s3));
    rm = fmaxf(rm, __shfl_xor(rm, 1));
    rm = fmaxf(rm, __shfl_xor(rm, 2));
    rm = fmaxf(rm, __shfl_xor(rm, 4));
    rm = fmaxf(rm, __shfl_xor(rm, 8));
    float nm = fmaxf(mrun[jj], rm);
    float al = __expf(mrun[jj] - nm);
    mrun[jj] = nm;
    float p0 = __expf(s0 - nm), p1 = __expf(s1 - nm);
    float p2 = __expf(s2 - nm), p3 = __expf(s3 - nm);
    float ps = p0 + p1 + p2 + p3;
    ps += __shfl_xor(ps, 1);
    ps += __shfl_xor(ps, 2);
    ps += __shfl_xor(ps, 4);
    ps += __shfl_xor(ps, 8);
    lrun[jj] = lrun[jj] * al + ps;
    alpha[jj] = al;
    short* pr = (short*)(PlB + (l4 * 4 + jj) * 144);
    pr[l15]      = f2bf(p0);
    pr[16 + l15] = f2bf(p1);
    pr[32 + l15] = f2bf(p2);
    pr[48 + l15] = f2bf(p3);
  }
#pragma unroll
  for (int db = 0; db < 4; db++) {
    f32x4 a = acc[db];
    a[0] *= alpha[0]; a[1] *= alpha[1]; a[2] *= alpha[2]; a[3] *= alpha[3];
    acc[db] = a;
  }
#pragma unroll
  for (int kc = 0; kc < 2; kc++) {
    short8 pf = *(const short8*)(PlB + l15 * 144 + kc * 64 + l4 * 16);
#pragma unroll
    for (int db = 0; db < 4; db++) {
      int d = db * 16 + l15;
      int cs = (kc * 4 + l4) ^ ((d >> 3) & 7);
      short8 vf = *(const short8*)(VtB + bufP * 9216 + d * 144 + cs * 16);
      acc[db] = __builtin_amdgcn_mfma_f32_16x16x32_bf16(pf, vf, acc[db], 0, 0, 0);
    }
  }
}

__global__ __launch_bounds__(256) void attn_mfma(const short* __restrict__ qkv, short* __restrict__ ctx) {
  __shared__ alignas(16) short Ks[2 * 64 * 64];
  __shared__ alignas(16) short Vt[2 * 64 * 72];
  __shared__ alignas(16) short Pl[4][16 * 72];
  const int t = threadIdx.x;
  const int l = t & 63;
  const int w = t >> 6;
  const int l15 = l & 15, l4 = l >> 4;
  const int bh = blockIdx.x;
  const int b = bh >> 4, h = bh & 15;
  const int qt = (gridDim.y - 1) - blockIdx.y;
  const int q0 = qt * 64 + w * 16;

  const short* base = qkv + (size_t)b * SEQ * 3072 + h * 64;

  short8 qf[2];
#pragma unroll
  for (int c = 0; c < 2; c++)
    qf[c] = *(const short8*)(base + (size_t)(q0 + l15) * 3072 + c * 32 + l4 * 8);

  const int vr = t >> 3;
  const int vd0 = (t & 7) * 8;
  const short* vbase = base + 2048 + vd0;

  char* KsB = (char*)Ks;
  char* VtB = (char*)Vt;
  char* PlB = (char*)&Pl[w][0];

  short8 va0, vb0, va1, vb1;
  va0 = *(const short8*)(vbase + (size_t)(2 * vr) * 3072);
  vb0 = *(const short8*)(vbase + (size_t)(2 * vr + 1) * 3072);
  if (qt >= 1) {
    va1 = *(const short8*)(vbase + (size_t)(64 + 2 * vr) * 3072);
    vb1 = *(const short8*)(vbase + (size_t)(64 + 2 * vr + 1) * 3072);
  }
#pragma unroll
  for (int i = 0; i < 8; i++) {
    int d = vd0 + i;
    int cs = (vr >> 2) ^ ((d >> 3) & 7);
    uint32_t val = (uint32_t)(uint16_t)va0[i] | ((uint32_t)(uint16_t)vb0[i] << 16);
    *(uint32_t*)(VtB + d * 144 + cs * 16 + (vr & 3) * 4) = val;
  }
#pragma unroll
  for (int i = 0; i < 2; i++) {
    int g = (w * 2 + i) * 64 + l;
    int key = g >> 3, ck = g & 7;
    const short* src = base + (size_t)key * 3072 + 1024 + ((ck ^ (key & 7)) * 8);
    __builtin_amdgcn_global_load_lds((gas_ptr)src, (las_ptr)(KsB + g * 16), 16, 0, 0);
  }
  __syncthreads();

  f32x4 acc[4] = {};
  float mrun[4] = {-1e30f, -1e30f, -1e30f, -1e30f};
  float lrun[4] = {0.f, 0.f, 0.f, 0.f};

  int kt = 0;
  while (true) {
    attn_step(kt, qt, 0, base, vbase, va1, vb1, va0, vb0, qf,
              KsB, VtB, PlB, acc, mrun, lrun, w, l, q0, vr, vd0);
    __syncthreads();
    if (++kt > qt) break;
    attn_step(kt, qt, 1, base, vbase, va0, vb0, va1, vb1, qf,
              KsB, VtB, PlB, acc, mrun, lrun, w, l, q0, vr, vd0);
    __syncthreads();
    if (++kt > qt) break;
  }

  float inv[4];
#pragma unroll
  for (int jj = 0; jj < 4; jj++) inv[jj] = 1.0f / lrun[jj];
  short* obase = ctx + (size_t)(b * SEQ + q0) * D_MODEL + h * 64;
#pragma unroll
  for (int db = 0; db < 4; db++)
#pragma unroll
    for (int jj = 0; jj < 4; jj++)
      obase[(size_t)(l4 * 4 + jj) * D_MODEL + db * 16 + l15] = f2bf(acc[db][jj] * inv[jj]);
}

extern "C" void kernel_launch(void* const* d_in, const int* in_sizes, int n_in,
                              void* d_out, int out_size, void* d_ws, size_t ws_size,
                              hipStream_t stream) {
  (void)in_sizes; (void)n_in; (void)out_size; (void)ws_size;
  const float* x    = (const float*)d_in[0];
  const float* WQ   = (const float*)d_in[1];
  const float* WK   = (const float*)d_in[2];
  const float* WV   = (const float*)d_in[3];
  const float* WO   = (const float*)d_in[4];
  const float* W1   = (const float*)d_in[5];
  const float* b1   = (const float*)d_in[6];
  const float* W2   = (const float*)d_in[7];
  const float* b2   = (const float*)d_in[8];
  const float* ln1w = (const float*)d_in[9];
  const float* ln1b = (const float*)d_in[10];
  const float* ln2w = (const float*)d_in[11];
  const float* ln2b = (const float*)d_in[12];
  float* out = (float*)d_out;

  char* p = (char*)d_ws;
  short* h1    = (short*)p; p += (size_t)ROWS * D_MODEL * 2;        // 8 MB
  short* ctx   = (short*)p; p += (size_t)ROWS * D_MODEL * 2;        // 8 MB
  short* h2    = (short*)p; p += (size_t)ROWS * D_MODEL * 2;        // 8 MB
  short* m1    = (short*)p; p += (size_t)ROWS * DMLP * 2;           // 32 MB
  short* wqkvT = (short*)p; p += (size_t)3 * D_MODEL * D_MODEL * 2; // 6 MB
  short* woT   = (short*)p; p += (size_t)D_MODEL * D_MODEL * 2;     // 2 MB
  short* w1T   = (short*)p; p += (size_t)D_MODEL * DMLP * 2;        // 8 MB
  short* w2T   = (short*)p; p += (size_t)D_MODEL * DMLP * 2;        // 8 MB
  short* qkv   = (short*)p; p += (size_t)ROWS * 3 * D_MODEL * 2;    // 24 MB

  // split-K partial (16 MB f32) in qkv region (dead after attention)
  float* fp1 = (float*)qkv;

  // weight repacks (bf16, B^T layout)
  transpose_tile<<<dim3(1, 16, 16), 256, 0, stream>>>(WQ, wqkvT,                   1024, 64, D_MODEL * DHEAD);
  transpose_tile<<<dim3(1, 16, 16), 256, 0, stream>>>(WK, wqkvT + 1024 * 1024,     1024, 64, D_MODEL * DHEAD);
  transpose_tile<<<dim3(1, 16, 16), 256, 0, stream>>>(WV, wqkvT + 2 * 1024 * 1024, 1024, 64, D_MODEL * DHEAD);
  transpose_tile<<<dim3(16, 16, 1), 256, 0, stream>>>(WO, woT, 1024, 1024, 0);
  transpose_tile<<<dim3(64, 16, 1), 256, 0, stream>>>(W1, w1T, 1024, 4096, 0);
  transpose_tile<<<dim3(16, 64, 1), 256, 0, stream>>>(W2, w2T, 4096, 1024, 0);

  // LN1
  ln_kernel<<<ROWS, 256, 0, stream>>>(x, ln1w, ln1b, h1);
  // QKV projection -> bf16 qkv  (nx=24)
  gemm_bt<0><<<dim3(3 * D_MODEL / 128, ROWS / 128), 256, 0, stream>>>(
      h1, wqkvT, nullptr, nullptr, nullptr, qkv, nullptr,
      ROWS, 3 * D_MODEL, D_MODEL, D_MODEL, D_MODEL);
  // attention
  attn_mfma<<<dim3(BATCH * NHEADS, SEQ / 64), 256, 0, stream>>>(qkv, ctx);
  // output projection, split-K z=2: z0 -> out = v + x ; z1 -> fp1  (nx=8)
  gemm_bt<5><<<dim3(D_MODEL / 128, ROWS / 128, 2), 256, 0, stream>>>(
      ctx, woT, nullptr, x, out, nullptr, fp1,
      ROWS, D_MODEL, D_MODEL / 2, D_MODEL, D_MODEL);
  // fused: out += fp1 ; h2 = LN2(out)
  reduce_ln<<<ROWS, 256, 0, stream>>>(out, fp1, ln2w, ln2b, h2);
  // MLP fc1 + GELU -> bf16 m1  (nx=32)
  gemm_bt<2><<<dim3(DMLP / 128, ROWS / 128), 256, 0, stream>>>(
      h2, w1T, b1, nullptr, nullptr, m1, nullptr,
      ROWS, DMLP, D_MODEL, D_MODEL, D_MODEL);
  // MLP fc2, split-K z=2: z0 -> out = v + b2 + resid(out) ; z1 -> fp1  (nx=8)
  gemm_bt<5><<<dim3(D_MODEL / 128, ROWS / 128, 2), 256, 0, stream>>>(
      m1, w2T, b2, out, out, nullptr, fp1,
      ROWS, D_MODEL, DMLP / 2, DMLP, DMLP);
  reduce1<<<2048, 256, 0, stream>>>(out, fp1, ROWS * D_MODEL / 4);
}